// Round 4
// baseline (279.484 us; speedup 1.0000x reference)
//
#include <hip/hip_runtime.h>
#include <math.h>

// Problem constants
#define B_DIM 8
#define A_DIM 48
#define GF_DIM 256
#define S_DIM 4096
#define P_DIM 32
#define E_DIM 5
#define OHN 100
#define NBINS 65536

typedef __attribute__((ext_vector_type(8))) short short8v;
typedef __attribute__((ext_vector_type(4))) float float4v;

// ---------------- helpers ----------------
__device__ __forceinline__ float wave_sum(float v) {
#pragma unroll
    for (int o = 32; o; o >>= 1) v += __shfl_xor(v, o, 64);
    return v;
}
__device__ __forceinline__ float wave_max(float v) {
#pragma unroll
    for (int o = 32; o; o >>= 1) v = fmaxf(v, __shfl_xor(v, o, 64));
    return v;
}
__device__ __forceinline__ float quad16_sum(float v) {
    v += __shfl_xor(v, 1, 64); v += __shfl_xor(v, 2, 64);
    v += __shfl_xor(v, 4, 64); v += __shfl_xor(v, 8, 64);
    return v;
}
__device__ __forceinline__ unsigned short bf16_rn(float x) {
    unsigned int u = __float_as_uint(x);
    return (unsigned short)((u + 0x7FFFu + ((u >> 16) & 1u)) >> 16);
}
__device__ __forceinline__ float bf16_val(unsigned short h) {
    return __uint_as_float(((unsigned int)h) << 16);
}
__device__ __forceinline__ float4v mfma_bf16(short8v a, short8v b, float4v c) {
    return __builtin_amdgcn_mfma_f32_16x16x32_bf16(a, b, c, 0, 0, 0);
}

// ---------------- prep: W hi/lo streams + vert*mask^2 + mask/ei + zero spect -
// (unchanged from the 110.7us R1 kernel)
__global__ __launch_bounds__(256) void k_prep(
    const float* __restrict__ cW, const float* __restrict__ l1W,
    const float* __restrict__ l2aW, const float* __restrict__ l2bW,
    const float* __restrict__ vert_feat, const float* __restrict__ vert_mask,
    const float* __restrict__ elem_oh,
    short* __restrict__ wp, short* __restrict__ wv,
    float* __restrict__ maskB, int* __restrict__ eiB,
    float4* __restrict__ spect4)
{
    const int blk = blockIdx.x;
    const int tid = threadIdx.x;
    if (blk < 1152) {
        int e = blk * 256 + tid;              // < 36*8192
        int c = e >> 13;
        int i = e & 8191;
        int j    = i & 7;
        int lane = (i >> 3) & 63;
        int nt   = (i >> 9) & 1;
        int wn   = i >> 10;
        int krel = (lane >> 4) * 8 + j;
        int n    = wn * 32 + nt * 16 + (lane & 15);
        float val = 0.f;
        if (c < 12) {
            int kp = c * 32 + krel;
            if (kp < 100)       val = cW[kp * 256 + n];
            else if (kp >= 128) val = cW[(kp - 28) * 256 + n];
        } else {
            int L  = (c - 12) >> 3;
            int kc = (c - 12) & 7;
            const float* W = (L == 0) ? l1W : (L == 1) ? l2aW : l2bW;
            val = W[(kc * 32 + krel) * 256 + n];
        }
        unsigned short h = bf16_rn(val);
        float lo = val - bf16_val(h);
        int base = c * 16384 + (i & 511);
        wp[base + (wn * 4 + nt) * 512]     = (short)h;
        wp[base + (wn * 4 + 2 + nt) * 512] = (short)bf16_rn(lo);
    } else if (blk < 1664) {
        int vb = blk - 1152;
        int vc = vb >> 5;                     // 0..15
        int i  = (vb & 31) * 256 + tid;       // 0..8191
        int b  = vc >> 1, v = vc & 1;
        int j    = i & 7;
        int lane = (i >> 3) & 63;
        int nt   = (i >> 9) & 1;
        int wn   = i >> 10;
        int k = v * 32 + (lane >> 4) * 8 + j;
        int n = wn * 32 + nt * 16 + (lane & 15);
        float val = 0.f;
        if (k < A_DIM) {
            float mk = vert_mask[b * A_DIM + k];
            val = vert_feat[((size_t)(b * A_DIM + k)) * GF_DIM + n] * mk * mk;
        }
        unsigned short h = bf16_rn(val);
        float lo = val - bf16_val(h);
        int base = vc * 16384 + (i & 511);
        wv[base + (wn * 4 + nt) * 512]     = (short)h;
        wv[base + (wn * 4 + 2 + nt) * 512] = (short)bf16_rn(lo);
    } else if (blk == 1664) {
        // grid-stride: 384 entries with 256 threads
        for (int t = tid; t < B_DIM * A_DIM; t += 256) {
            maskB[t] = vert_mask[t];
            int ei = 0;
#pragma unroll
            for (int e = 0; e < E_DIM; ++e)
                if (elem_oh[t * E_DIM + e] > 0.5f) ei = e;
            eiB[t] = ei;
        }
    } else {
        // zero spect: 512 blocks x 256 thr x float4 = 524288 f32
        int z = (blk - 1665) * 256 + tid;
        spect4[z] = make_float4(0.f, 0.f, 0.f, 0.f);
    }
}

// ---------------- MLP kernel: M=64 rows/block, 512 blocks, 2 blocks/CU -----
// R3 POST-MORTEM: A-frag ping-pong at fixed geometry regressed (110->132us,
// no spills) — compiler's natural schedule was better. This round changes
// GEOMETRY instead: M 32->64 per block. Same W slice feeds 2x MFMAs
// (24 vs 12 MFMA per kc per wave), W L2 traffic halves (0.6 GB), grid 512.
// launch_bounds(512,4) -> 2 blocks/CU -> 128-VGPR cap (headroom, no spill).
// LDS layout (68864 B -> 2 blocks/CU):
//   xAh  [0,     32768)  8 chunks x 4 mi (inter-layer hi)
//   xAl  [32768, 65536)  lo; fm (8192 B) aliased at xAl base
//   ps   [65536, 67584)  8 x 64 f32
//   tm   [67584, 68608)  64 rows x 16 B thermometer bitmask
//   invsz[68608, 68864)  256
#define L_XAL 32768
#define L_PS  65536
#define L_TM  67584
#define L_INV 68608
#define L_TOT 68864

// One GEMM layer, barrier-free K loop; W slice in regs (depth-2 ring, one-kc
// lookahead — fits the 128-VGPR cap alongside acc[4][2]).
// THERM: kc 0..3 A-frags regenerated from thermometer bitmask (exact bf16,
// hi-only, 2 mfma); kc 4..11 read xAh/xAl chunk kc-4 (3 mfma).
template <int NKC, int ACT, bool NORM, bool SCORE, bool THERM>
__device__ __forceinline__ void layer_pass(
    short* xAh, short* xAl, float (*ps)[64], const uint4* __restrict__ tm,
    const short* __restrict__ wstream, const float* __restrict__ bias,
    const float* __restrict__ sW, const float* __restrict__ sb,
    float* __restrict__ scores, int R0)
{
    const int tid  = threadIdx.x;
    const int lane = tid & 63;
    const int wn   = tid >> 6;
    const int quad = lane >> 4;
    const int col  = lane & 15;
    const short* wbase = wstream + wn * 2048 + lane * 8;

    // packed thermometer bits: tw[kc] holds byte(mi) at bits [mi*8, mi*8+8):
    // bit (mi*8+j) = therm bit k = kc*32 + quad*8 + j of row mi*16+col.
    unsigned int tw0 = 0, tw1 = 0, tw2 = 0, tw3 = 0;
    if (THERM) {
        const int sh = quad * 8;
        uint4 t0 = tm[col];
        uint4 t1 = tm[16 + col];
        uint4 t2 = tm[32 + col];
        uint4 t3 = tm[48 + col];
        tw0 = ((t0.x >> sh) & 0xFFu)        | (((t1.x >> sh) & 0xFFu) << 8)
            | (((t2.x >> sh) & 0xFFu) << 16) | (((t3.x >> sh) & 0xFFu) << 24);
        tw1 = ((t0.y >> sh) & 0xFFu)        | (((t1.y >> sh) & 0xFFu) << 8)
            | (((t2.y >> sh) & 0xFFu) << 16) | (((t3.y >> sh) & 0xFFu) << 24);
        tw2 = ((t0.z >> sh) & 0xFFu)        | (((t1.z >> sh) & 0xFFu) << 8)
            | (((t2.z >> sh) & 0xFFu) << 16) | (((t3.z >> sh) & 0xFFu) << 24);
        tw3 = ((t0.w >> sh) & 0xFFu)        | (((t1.w >> sh) & 0xFFu) << 8)
            | (((t2.w >> sh) & 0xFFu) << 16) | (((t3.w >> sh) & 0xFFu) << 24);
    }

    float4v acc[4][2];
#pragma unroll
    for (int mi = 0; mi < 4; ++mi)
#pragma unroll
        for (int nt = 0; nt < 2; ++nt) acc[mi][nt] = (float4v){0.f, 0.f, 0.f, 0.f};

    // depth-2 W ring (one-kc lookahead): 32 regs of W state
    short8v bh[2][2], bl[2][2];
    {
        const short* q = wbase;
        bh[0][0] = *(const short8v*)(q);
        bh[0][1] = *(const short8v*)(q + 512);
        bl[0][0] = *(const short8v*)(q + 1024);
        bl[0][1] = *(const short8v*)(q + 1536);
    }

#pragma unroll
    for (int kc = 0; kc < NKC; ++kc) {
        const int cur = kc & 1;
        if (kc + 1 < NKC) {
            const int nxt = (kc + 1) & 1;
            const short* q = wbase + (kc + 1) * 16384;
            bh[nxt][0] = *(const short8v*)(q);
            bh[nxt][1] = *(const short8v*)(q + 512);
            bl[nxt][0] = *(const short8v*)(q + 1024);
            bl[nxt][1] = *(const short8v*)(q + 1536);
        }
        const bool isT = THERM && (kc < 4);
        short8v ah[4], al[4];
        if (isT) {
            const unsigned int w = (kc == 0) ? tw0 : (kc == 1) ? tw1
                                 : (kc == 2) ? tw2 : tw3;
#pragma unroll
            for (int mi = 0; mi < 4; ++mi) {
                short8v hv;
#pragma unroll
                for (int j = 0; j < 8; ++j)
                    hv[j] = (short)(((w >> (mi * 8 + j)) & 1u) ? 0x3F80 : 0);
                ah[mi] = hv;
            }
        } else {
            const int ki = THERM ? (kc - 4) : kc;
#pragma unroll
            for (int mi = 0; mi < 4; ++mi) {
                ah[mi] = *(const short8v*)(xAh + ((ki * 4 + mi) * 64 + lane) * 8);
                al[mi] = *(const short8v*)(xAl + ((ki * 4 + mi) * 64 + lane) * 8);
            }
        }
#pragma unroll
        for (int mi = 0; mi < 4; ++mi)
#pragma unroll
            for (int nt = 0; nt < 2; ++nt) {
                acc[mi][nt] = mfma_bf16(ah[mi], bh[cur][nt], acc[mi][nt]);
                acc[mi][nt] = mfma_bf16(ah[mi], bl[cur][nt], acc[mi][nt]);
                if (!isT)
                    acc[mi][nt] = mfma_bf16(al[mi], bh[cur][nt], acc[mi][nt]);
            }
    }

    // bias + activation
    float bc0 = bias[wn * 32 + col];
    float bc1 = bias[wn * 32 + 16 + col];
#pragma unroll
    for (int mi = 0; mi < 4; ++mi)
#pragma unroll
        for (int r = 0; r < 4; ++r) {
            float z0 = acc[mi][0][r] + bc0;
            float z1 = acc[mi][1][r] + bc1;
            if (ACT == 0) { z0 = fmaxf(z0, 0.f); z1 = fmaxf(z1, 0.f); }
            else { z0 = (z0 > 0.f) ? z0 : 0.01f * z0; z1 = (z1 > 0.f) ? z1 : 0.01f * z1; }
            acc[mi][0][r] = z0; acc[mi][1][r] = z1;
        }

    __syncthreads();   // all xA reads of this layer done

    if (NORM) {
        float rsum[4][4];
#pragma unroll
        for (int mi = 0; mi < 4; ++mi)
#pragma unroll
            for (int r = 0; r < 4; ++r)
                rsum[mi][r] = quad16_sum(acc[mi][0][r] + acc[mi][1][r]);
        if (col == 0) {
#pragma unroll
            for (int mi = 0; mi < 4; ++mi)
#pragma unroll
                for (int r = 0; r < 4; ++r)
                    ps[wn][mi * 16 + quad * 4 + r] = rsum[mi][r];
        }
        __syncthreads();
        float mu[4][4];
#pragma unroll
        for (int mi = 0; mi < 4; ++mi)
#pragma unroll
            for (int r = 0; r < 4; ++r) {
                int m = mi * 16 + quad * 4 + r;
                float s = 0.f;
#pragma unroll
                for (int w = 0; w < 8; ++w) s += ps[w][m];
                mu[mi][r] = s * (1.f / 256.f);
            }
        __syncthreads();
        float qs[4][4];
#pragma unroll
        for (int mi = 0; mi < 4; ++mi)
#pragma unroll
            for (int r = 0; r < 4; ++r) {
                acc[mi][0][r] -= mu[mi][r];
                acc[mi][1][r] -= mu[mi][r];
                float q = acc[mi][0][r] * acc[mi][0][r]
                        + acc[mi][1][r] * acc[mi][1][r];
                qs[mi][r] = quad16_sum(q);
            }
        if (col == 0) {
#pragma unroll
            for (int mi = 0; mi < 4; ++mi)
#pragma unroll
                for (int r = 0; r < 4; ++r)
                    ps[wn][mi * 16 + quad * 4 + r] = qs[mi][r];
        }
        __syncthreads();
#pragma unroll
        for (int mi = 0; mi < 4; ++mi)
#pragma unroll
            for (int r = 0; r < 4; ++r) {
                int m = mi * 16 + quad * 4 + r;
                float s = 0.f;
#pragma unroll
                for (int w = 0; w < 8; ++w) s += ps[w][m];
                float rsf = 1.0f / sqrtf(s * (1.f / 256.f) + 1e-5f);
                acc[mi][0][r] *= rsf;
                acc[mi][1][r] *= rsf;
            }
    }

    if (SCORE) {
        __syncthreads();
        float sv0 = sW[wn * 32 + col];
        float sv1 = sW[wn * 32 + 16 + col];
        float psu[4][4];
#pragma unroll
        for (int mi = 0; mi < 4; ++mi)
#pragma unroll
            for (int r = 0; r < 4; ++r)
                psu[mi][r] = quad16_sum(acc[mi][0][r] * sv0 + acc[mi][1][r] * sv1);
        if (col == 0) {
#pragma unroll
            for (int mi = 0; mi < 4; ++mi)
#pragma unroll
                for (int r = 0; r < 4; ++r)
                    ps[wn][mi * 16 + quad * 4 + r] = psu[mi][r];
        }
        __syncthreads();
        if (tid < 64) {
            float s = sb[0];
#pragma unroll
            for (int w = 0; w < 8; ++w) s += ps[w][tid];
            scores[R0 + tid] = s;
        }
    } else {
        // writeback to next layer's A-frag layout; wave wn owns k-chunk wn.
#pragma unroll
        for (int mi = 0; mi < 4; ++mi)
#pragma unroll
            for (int nt = 0; nt < 2; ++nt) {
                int nn0 = (nt * 16 + col) & ~1;
                int q2  = nn0 >> 3;
                int j0  = nn0 & 7;
#pragma unroll
                for (int r = 0; r < 4; ++r) {
                    float v  = acc[mi][nt][r];
                    float pv = __shfl_xor(v, 1, 64);
                    int m15 = quad * 4 + r;
                    int rowidx = (wn * 4 + mi) * 64 + q2 * 16 + m15;
                    if ((col & 1) == 0) {
                        unsigned int wd = (unsigned int)bf16_rn(v)
                                        | ((unsigned int)bf16_rn(pv) << 16);
                        ((unsigned int*)xAh)[rowidx * 4 + (j0 >> 1)] = wd;
                    } else {
                        float ls = v  - bf16_val(bf16_rn(v));
                        float lp = pv - bf16_val(bf16_rn(pv));
                        unsigned int wd = (unsigned int)bf16_rn(lp)
                                        | ((unsigned int)bf16_rn(ls) << 16);
                        ((unsigned int*)xAl)[rowidx * 4 + (j0 >> 1)] = wd;
                    }
                }
            }
        __syncthreads();
    }
}

__global__ __launch_bounds__(512, 4) void k_mlp(
    const int* __restrict__ subsets, const short* __restrict__ wprep,
    const short* __restrict__ vertB,
    const float* __restrict__ maskB, const int* __restrict__ eiB,
    const float* __restrict__ cb,  const float* __restrict__ l1b,
    const float* __restrict__ l2ab, const float* __restrict__ l2bb,
    const float* __restrict__ sW,  const float* __restrict__ sb,
    float* __restrict__ scores)
{
    __shared__ __align__(16) char smem[L_TOT];
    short*  xAh = (short*)smem;
    short*  xAl = (short*)(smem + L_XAL);
    short*  fm  = (short*)(smem + L_XAL);          // alias: dead before xAl use
    float (*ps)[64]  = (float(*)[64])(smem + L_PS);
    uint4*  tm       = (uint4*)(smem + L_TM);
    float*  invsz    = (float*)(smem + L_INV);

    const int tid  = threadIdx.x;
    const int lane = tid & 63;
    const int wn   = tid >> 6;
    const int quad = lane >> 4;
    const int col  = lane & 15;
    const int fb   = blockIdx.x;          // 0..511, 64 rows each
    const int b    = fb >> 6;
    const int R0   = fb * 64;

    // ---- phase A1: subset flags -> exact-bf16 A-frags (K=64, k>=48 zero) ----
    {
        int g  = tid;                     // 512 threads = 8 frags x 64 lanes
        int lg = g & 63;
        int t2 = g >> 6;                  // kc*4 + mi
        int kc = t2 >> 2, mi = t2 & 3;
        int m  = mi * 16 + (lg & 15);
        int k0 = kc * 32 + (lg >> 4) * 8;
        const int* srow = subsets + (size_t)(R0 + m) * A_DIM;
        short8v hv;
#pragma unroll
        for (int j = 0; j < 8; ++j) {
            int k = k0 + j;
            hv[j] = (short)((k < A_DIM && srow[k]) ? 0x3F80 : 0);
        }
        *(short8v*)(fm + g * 8) = hv;
    }

    // ---- phase A2: per-row thermometer bitmask (ballot) + 1/subset_size ----
    {
        const float mymask = (lane < A_DIM) ? maskB[b * A_DIM + lane] : 0.f;
        const int   myei   = (lane < A_DIM) ? eiB[b * A_DIM + lane]   : -1;
        unsigned long long* tmw = (unsigned long long*)tm;
#pragma unroll
        for (int i = 0; i < 8; ++i) {
            int r = wn * 8 + i;
            int fl = (lane < A_DIM) ? subsets[(size_t)(R0 + r) * A_DIM + lane] : 0;
            unsigned long long m0 = __ballot(fl != 0 && myei == 0);
            unsigned long long m1 = __ballot(fl != 0 && myei == 1);
            unsigned long long m2 = __ballot(fl != 0 && myei == 2);
            unsigned long long m3 = __ballot(fl != 0 && myei == 3);
            unsigned long long m4 = __ballot(fl != 0 && myei == 4);
            float ssz = wave_sum(fl ? mymask : 0.f) + 1e-4f;
            if (lane == 0) {
                unsigned int c0 = __popcll(m0), c1 = __popcll(m1),
                             c2 = __popcll(m2), c3 = __popcll(m3),
                             c4 = __popcll(m4);
                // thermometer run per element: bits [e*20, e*20+min(c,20))
                unsigned long long r0 = (1ull << (c0 > 20u ? 20u : c0)) - 1ull;
                unsigned long long r1 = (1ull << (c1 > 20u ? 20u : c1)) - 1ull;
                unsigned long long r2 = (1ull << (c2 > 20u ? 20u : c2)) - 1ull;
                unsigned long long r3 = (1ull << (c3 > 20u ? 20u : c3)) - 1ull;
                unsigned long long r4 = (1ull << (c4 > 20u ? 20u : c4)) - 1ull;
                unsigned long long lo = r0 | (r1 << 20) | (r2 << 40) | (r3 << 60);
                unsigned long long hi = (r3 >> 4) | (r4 << 16);
                tmw[r * 2]     = lo;
                tmw[r * 2 + 1] = hi;
                invsz[r]  = 1.0f / ssz;
            }
        }
    }
    __syncthreads();

    // ---- layer 0: sws = flags @ (vert*mask^2), /size, inorm -> combine input
    {
        const short* wbase = vertB + b * 32768 + wn * 2048 + lane * 8;
        float4v acc[4][2];
#pragma unroll
        for (int mi = 0; mi < 4; ++mi)
#pragma unroll
            for (int nt = 0; nt < 2; ++nt) acc[mi][nt] = (float4v){0.f, 0.f, 0.f, 0.f};

        short8v bh[2][2], bl[2][2];
#pragma unroll
        for (int kc = 0; kc < 2; ++kc) {
            const short* q = wbase + kc * 16384;
            bh[kc][0] = *(const short8v*)(q);
            bh[kc][1] = *(const short8v*)(q + 512);
            bl[kc][0] = *(const short8v*)(q + 1024);
            bl[kc][1] = *(const short8v*)(q + 1536);
        }
#pragma unroll
        for (int kc = 0; kc < 2; ++kc) {
#pragma unroll
            for (int mi = 0; mi < 4; ++mi) {
                short8v a = *(const short8v*)(fm + ((kc * 4 + mi) * 64 + lane) * 8);
#pragma unroll
                for (int nt = 0; nt < 2; ++nt) {
                    acc[mi][nt] = mfma_bf16(a, bh[kc][nt], acc[mi][nt]);
                    acc[mi][nt] = mfma_bf16(a, bl[kc][nt], acc[mi][nt]);
                }
            }
        }

        // mean = sws / subset_size
#pragma unroll
        for (int mi = 0; mi < 4; ++mi)
#pragma unroll
            for (int r = 0; r < 4; ++r) {
                float iv = invsz[mi * 16 + quad * 4 + r];
                acc[mi][0][r] *= iv;
                acc[mi][1][r] *= iv;
            }

        __syncthreads();   // fm reads done; xAl region may now be overwritten

        // instance norm over 256 cols
        {
            float rsum[4][4];
#pragma unroll
            for (int mi = 0; mi < 4; ++mi)
#pragma unroll
                for (int r = 0; r < 4; ++r)
                    rsum[mi][r] = quad16_sum(acc[mi][0][r] + acc[mi][1][r]);
            if (col == 0) {
#pragma unroll
                for (int mi = 0; mi < 4; ++mi)
#pragma unroll
                    for (int r = 0; r < 4; ++r)
                        ps[wn][mi * 16 + quad * 4 + r] = rsum[mi][r];
            }
            __syncthreads();
            float mu[4][4];
#pragma unroll
            for (int mi = 0; mi < 4; ++mi)
#pragma unroll
                for (int r = 0; r < 4; ++r) {
                    int m = mi * 16 + quad * 4 + r;
                    float s = 0.f;
#pragma unroll
                    for (int w = 0; w < 8; ++w) s += ps[w][m];
                    mu[mi][r] = s * (1.f / 256.f);
                }
            __syncthreads();
            float qs[4][4];
#pragma unroll
            for (int mi = 0; mi < 4; ++mi)
#pragma unroll
                for (int r = 0; r < 4; ++r) {
                    acc[mi][0][r] -= mu[mi][r];
                    acc[mi][1][r] -= mu[mi][r];
                    float q = acc[mi][0][r] * acc[mi][0][r]
                            + acc[mi][1][r] * acc[mi][1][r];
                    qs[mi][r] = quad16_sum(q);
                }
            if (col == 0) {
#pragma unroll
                for (int mi = 0; mi < 4; ++mi)
#pragma unroll
                    for (int r = 0; r < 4; ++r)
                        ps[wn][mi * 16 + quad * 4 + r] = qs[mi][r];
            }
            __syncthreads();
#pragma unroll
            for (int mi = 0; mi < 4; ++mi)
#pragma unroll
                for (int r = 0; r < 4; ++r) {
                    int m = mi * 16 + quad * 4 + r;
                    float s = 0.f;
#pragma unroll
                    for (int w = 0; w < 8; ++w) s += ps[w][m];
                    float rsf = 1.0f / sqrtf(s * (1.f / 256.f) + 1e-5f);
                    acc[mi][0][r] *= rsf;
                    acc[mi][1][r] *= rsf;
                }
        }

        // writeback: normed cols n -> combine chunks wn (layer 1 reads kc-4)
#pragma unroll
        for (int mi = 0; mi < 4; ++mi)
#pragma unroll
            for (int nt = 0; nt < 2; ++nt) {
                int nn0 = (nt * 16 + col) & ~1;
                int q2  = nn0 >> 3;
                int j0  = nn0 & 7;
#pragma unroll
                for (int r = 0; r < 4; ++r) {
                    float v  = acc[mi][nt][r];
                    float pv = __shfl_xor(v, 1, 64);
                    int m15 = quad * 4 + r;
                    int rowidx = (wn * 4 + mi) * 64 + q2 * 16 + m15;
                    if ((col & 1) == 0) {
                        unsigned int wd = (unsigned int)bf16_rn(v)
                                        | ((unsigned int)bf16_rn(pv) << 16);
                        ((unsigned int*)xAh)[rowidx * 4 + (j0 >> 1)] = wd;
                    } else {
                        float ls = v  - bf16_val(bf16_rn(v));
                        float lp = pv - bf16_val(bf16_rn(pv));
                        unsigned int wd = (unsigned int)bf16_rn(lp)
                                        | ((unsigned int)bf16_rn(ls) << 16);
                        ((unsigned int*)xAl)[rowidx * 4 + (j0 >> 1)] = wd;
                    }
                }
            }
        __syncthreads();
    }

    // ---- layers 1..4 ----
    layer_pass<12, 0, true,  false, true >(xAh, xAl, ps, tm, wprep,
        cb, nullptr, nullptr, nullptr, R0);
    layer_pass< 8, 0, false, false, false>(xAh, xAl, ps, tm, wprep + 12 * 16384,
        l1b, nullptr, nullptr, nullptr, R0);
    layer_pass< 8, 1, false, false, false>(xAh, xAl, ps, tm, wprep + 20 * 16384,
        l2ab, nullptr, nullptr, nullptr, R0);
    layer_pass< 8, 0, true,  true,  false>(xAh, xAl, ps, tm, wprep + 28 * 16384,
        l2bb, sW, sb, scores, R0);
}

// ---------------- softmax / scatter ----------------
__global__ __launch_bounds__(256) void k_softmax(float* __restrict__ probs) {
    const int b   = blockIdx.x;
    const int tid = threadIdx.x;
    __shared__ float redA[4];
    __shared__ float redB[4];
    float* sp = probs + (size_t)b * S_DIM;

    float v[16];
    float mx = -INFINITY;
#pragma unroll
    for (int i = 0; i < 16; ++i) {
        v[i] = sp[tid + i * 256];
        mx = fmaxf(mx, v[i]);
    }
    mx = wave_max(mx);
    if ((tid & 63) == 0) redA[tid >> 6] = mx;
    __syncthreads();
    mx = fmaxf(fmaxf(redA[0], redA[1]), fmaxf(redA[2], redA[3]));

    float sum = 0.f;
#pragma unroll
    for (int i = 0; i < 16; ++i) {
        v[i] = expf(v[i] - mx);
        sum += v[i];
    }
    sum = wave_sum(sum);
    if ((tid & 63) == 0) redB[tid >> 6] = sum;
    __syncthreads();
    float tot = redB[0] + redB[1] + redB[2] + redB[3];
    float inv = 1.0f / tot;
#pragma unroll
    for (int i = 0; i < 16; ++i) sp[tid + i * 256] = v[i] * inv;
}

__global__ __launch_bounds__(256) void k_scatter(
    const int*   __restrict__ mass_idx,
    const float* __restrict__ intensity,
    const float* __restrict__ probs,
    float* __restrict__ spect)
{
    int i  = blockIdx.x * 256 + threadIdx.x;
    int bs = i >> 5;
    int b  = i >> 17;
    float w = intensity[i] * probs[bs];
    unsafeAtomicAdd(spect + ((size_t)b << 16) + mass_idx[i], w);
}

// ---------------- launch ----------------
extern "C" void kernel_launch(void* const* d_in, const int* in_sizes, int n_in,
                              void* d_out, int out_size, void* d_ws, size_t ws_size,
                              hipStream_t stream) {
    const float* vert_feat = (const float*)d_in[0];
    const float* vert_mask = (const float*)d_in[1];
    const float* elem_oh   = (const float*)d_in[2];
    const int*   subsets   = (const int*)d_in[4];
    const int*   mass_idx  = (const int*)d_in[6];
    const float* intensity = (const float*)d_in[7];
    const float* combine_W = (const float*)d_in[8];
    const float* combine_b = (const float*)d_in[9];
    const float* l1_W      = (const float*)d_in[10];
    const float* l1_b      = (const float*)d_in[11];
    const float* l2a_W     = (const float*)d_in[12];
    const float* l2a_b     = (const float*)d_in[13];
    const float* l2b_W     = (const float*)d_in[14];
    const float* l2b_b     = (const float*)d_in[15];
    const float* score_W   = (const float*)d_in[16];
    const float* score_b   = (const float*)d_in[17];

    float* out   = (float*)d_out;
    float* spect = out;                           // B*NBINS
    float* probs = out + (size_t)B_DIM * NBINS;   // B*S (scores -> probs in place)

    short* wprep = (short*)d_ws;                  // 36*16384 shorts
    short* vertB = wprep + 36 * 16384;            // 16*16384 shorts
    float* maskB = (float*)(vertB + 16 * 16384);  // 384 f32
    int*   eiB   = (int*)(maskB + B_DIM * A_DIM); // 384 int

    k_prep<<<2177, 256, 0, stream>>>(combine_W, l1_W, l2a_W, l2b_W,
        vert_feat, vert_mask, elem_oh, wprep, vertB, maskB, eiB,
        (float4*)spect);
    k_mlp<<<512, 512, 0, stream>>>(subsets, wprep, vertB, maskB, eiB,
        combine_b, l1_b, l2a_b, l2b_b, score_W, score_b, probs);
    k_softmax<<<B_DIM, 256, 0, stream>>>(probs);
    k_scatter<<<(B_DIM * S_DIM * P_DIM) / 256, 256, 0, stream>>>(
        mass_idx, intensity, probs, spect);
}

// Round 5
// 267.425 us; speedup vs baseline: 1.0451x; 1.0451x over previous
//
#include <hip/hip_runtime.h>
#include <math.h>

// Problem constants
#define B_DIM 8
#define A_DIM 48
#define GF_DIM 256
#define S_DIM 4096
#define P_DIM 32
#define E_DIM 5
#define OHN 100
#define NBINS 65536

typedef __attribute__((ext_vector_type(8))) short short8v;
typedef __attribute__((ext_vector_type(4))) float float4v;

// ---------------- helpers ----------------
__device__ __forceinline__ float wave_sum(float v) {
#pragma unroll
    for (int o = 32; o; o >>= 1) v += __shfl_xor(v, o, 64);
    return v;
}
__device__ __forceinline__ float wave_max(float v) {
#pragma unroll
    for (int o = 32; o; o >>= 1) v = fmaxf(v, __shfl_xor(v, o, 64));
    return v;
}
__device__ __forceinline__ float quad16_sum(float v) {
    v += __shfl_xor(v, 1, 64); v += __shfl_xor(v, 2, 64);
    v += __shfl_xor(v, 4, 64); v += __shfl_xor(v, 8, 64);
    return v;
}
__device__ __forceinline__ unsigned short bf16_rn(float x) {
    unsigned int u = __float_as_uint(x);
    return (unsigned short)((u + 0x7FFFu + ((u >> 16) & 1u)) >> 16);
}
__device__ __forceinline__ float bf16_val(unsigned short h) {
    return __uint_as_float(((unsigned int)h) << 16);
}
__device__ __forceinline__ float4v mfma_bf16(short8v a, short8v b, float4v c) {
    return __builtin_amdgcn_mfma_f32_16x16x32_bf16(a, b, c, 0, 0, 0);
}

// ---------------- prep: W hi/lo streams + vert*mask^2 + mask/ei + zero spect -
__global__ __launch_bounds__(256) void k_prep(
    const float* __restrict__ cW, const float* __restrict__ l1W,
    const float* __restrict__ l2aW, const float* __restrict__ l2bW,
    const float* __restrict__ vert_feat, const float* __restrict__ vert_mask,
    const float* __restrict__ elem_oh,
    short* __restrict__ wp, short* __restrict__ wv,
    float* __restrict__ maskB, int* __restrict__ eiB,
    float4* __restrict__ spect4)
{
    const int blk = blockIdx.x;
    const int tid = threadIdx.x;
    if (blk < 1152) {
        int e = blk * 256 + tid;              // < 36*8192
        int c = e >> 13;
        int i = e & 8191;
        int j    = i & 7;
        int lane = (i >> 3) & 63;
        int nt   = (i >> 9) & 1;
        int wn   = i >> 10;
        int krel = (lane >> 4) * 8 + j;
        int n    = wn * 32 + nt * 16 + (lane & 15);
        float val = 0.f;
        if (c < 12) {
            int kp = c * 32 + krel;
            if (kp < 100)       val = cW[kp * 256 + n];
            else if (kp >= 128) val = cW[(kp - 28) * 256 + n];
        } else {
            int L  = (c - 12) >> 3;
            int kc = (c - 12) & 7;
            const float* W = (L == 0) ? l1W : (L == 1) ? l2aW : l2bW;
            val = W[(kc * 32 + krel) * 256 + n];
        }
        unsigned short h = bf16_rn(val);
        float lo = val - bf16_val(h);
        int base = c * 16384 + (i & 511);
        wp[base + (wn * 4 + nt) * 512]     = (short)h;
        wp[base + (wn * 4 + 2 + nt) * 512] = (short)bf16_rn(lo);
    } else if (blk < 1664) {
        int vb = blk - 1152;
        int vc = vb >> 5;                     // 0..15
        int i  = (vb & 31) * 256 + tid;       // 0..8191
        int b  = vc >> 1, v = vc & 1;
        int j    = i & 7;
        int lane = (i >> 3) & 63;
        int nt   = (i >> 9) & 1;
        int wn   = i >> 10;
        int k = v * 32 + (lane >> 4) * 8 + j;
        int n = wn * 32 + nt * 16 + (lane & 15);
        float val = 0.f;
        if (k < A_DIM) {
            float mk = vert_mask[b * A_DIM + k];
            val = vert_feat[((size_t)(b * A_DIM + k)) * GF_DIM + n] * mk * mk;
        }
        unsigned short h = bf16_rn(val);
        float lo = val - bf16_val(h);
        int base = vc * 16384 + (i & 511);
        wv[base + (wn * 4 + nt) * 512]     = (short)h;
        wv[base + (wn * 4 + 2 + nt) * 512] = (short)bf16_rn(lo);
    } else if (blk == 1664) {
        // grid-stride: 384 entries with 256 threads
        for (int t = tid; t < B_DIM * A_DIM; t += 256) {
            maskB[t] = vert_mask[t];
            int ei = 0;
#pragma unroll
            for (int e = 0; e < E_DIM; ++e)
                if (elem_oh[t * E_DIM + e] > 0.5f) ei = e;
            eiB[t] = ei;
        }
    } else {
        // zero spect: 512 blocks x 256 thr x float4 = 524288 f32
        int z = (blk - 1665) * 256 + tid;
        spect4[z] = make_float4(0.f, 0.f, 0.f, 0.f);
    }
}

// ---------------- MLP kernel: M=64 rows/block, 512 blocks, 2 blocks/CU -----
// R4 POST-MORTEM: launch_bounds(512,4) empirically means 4 BLOCKS/CU on this
// compiler -> 8 waves/SIMD -> 64-VGPR cap -> the M=64 body (needs ~116 regs)
// spilled 95 MB to scratch. The geometry was never cleanly tested.
// THIS ROUND: single change — __launch_bounds__(512, 2) -> 2 blocks/CU ->
// 4 waves/SIMD -> 128-VGPR cap. LDS (69 KB) also gives 2 blocks/CU; both
// resources agree at 16 waves/CU (same residency as the 110us M=32 kernel,
// but 2x W reuse: 24 MFMA per 8 W-loads + 8 A-reads per kc per wave).
// LDS layout (68864 B):
//   xAh  [0,     32768)  8 chunks x 4 mi (inter-layer hi)
//   xAl  [32768, 65536)  lo; fm (8192 B) aliased at xAl base
//   ps   [65536, 67584)  8 x 64 f32
//   tm   [67584, 68608)  64 rows x 16 B thermometer bitmask
//   invsz[68608, 68864)  256
#define L_XAL 32768
#define L_PS  65536
#define L_TM  67584
#define L_INV 68608
#define L_TOT 68864

// One GEMM layer, barrier-free K loop; W slice in regs (depth-2 ring, one-kc
// lookahead — fits the 128-VGPR cap alongside acc[4][2]).
// THERM: kc 0..3 A-frags regenerated from thermometer bitmask (exact bf16,
// hi-only, 2 mfma); kc 4..11 read xAh/xAl chunk kc-4 (3 mfma).
template <int NKC, int ACT, bool NORM, bool SCORE, bool THERM>
__device__ __forceinline__ void layer_pass(
    short* xAh, short* xAl, float (*ps)[64], const uint4* __restrict__ tm,
    const short* __restrict__ wstream, const float* __restrict__ bias,
    const float* __restrict__ sW, const float* __restrict__ sb,
    float* __restrict__ scores, int R0)
{
    const int tid  = threadIdx.x;
    const int lane = tid & 63;
    const int wn   = tid >> 6;
    const int quad = lane >> 4;
    const int col  = lane & 15;
    const short* wbase = wstream + wn * 2048 + lane * 8;

    // packed thermometer bits: tw[kc] holds byte(mi) at bits [mi*8, mi*8+8):
    // bit (mi*8+j) = therm bit k = kc*32 + quad*8 + j of row mi*16+col.
    unsigned int tw0 = 0, tw1 = 0, tw2 = 0, tw3 = 0;
    if (THERM) {
        const int sh = quad * 8;
        uint4 t0 = tm[col];
        uint4 t1 = tm[16 + col];
        uint4 t2 = tm[32 + col];
        uint4 t3 = tm[48 + col];
        tw0 = ((t0.x >> sh) & 0xFFu)        | (((t1.x >> sh) & 0xFFu) << 8)
            | (((t2.x >> sh) & 0xFFu) << 16) | (((t3.x >> sh) & 0xFFu) << 24);
        tw1 = ((t0.y >> sh) & 0xFFu)        | (((t1.y >> sh) & 0xFFu) << 8)
            | (((t2.y >> sh) & 0xFFu) << 16) | (((t3.y >> sh) & 0xFFu) << 24);
        tw2 = ((t0.z >> sh) & 0xFFu)        | (((t1.z >> sh) & 0xFFu) << 8)
            | (((t2.z >> sh) & 0xFFu) << 16) | (((t3.z >> sh) & 0xFFu) << 24);
        tw3 = ((t0.w >> sh) & 0xFFu)        | (((t1.w >> sh) & 0xFFu) << 8)
            | (((t2.w >> sh) & 0xFFu) << 16) | (((t3.w >> sh) & 0xFFu) << 24);
    }

    float4v acc[4][2];
#pragma unroll
    for (int mi = 0; mi < 4; ++mi)
#pragma unroll
        for (int nt = 0; nt < 2; ++nt) acc[mi][nt] = (float4v){0.f, 0.f, 0.f, 0.f};

    // depth-2 W ring (one-kc lookahead): 32 regs of W state
    short8v bh[2][2], bl[2][2];
    {
        const short* q = wbase;
        bh[0][0] = *(const short8v*)(q);
        bh[0][1] = *(const short8v*)(q + 512);
        bl[0][0] = *(const short8v*)(q + 1024);
        bl[0][1] = *(const short8v*)(q + 1536);
    }

#pragma unroll
    for (int kc = 0; kc < NKC; ++kc) {
        const int cur = kc & 1;
        if (kc + 1 < NKC) {
            const int nxt = (kc + 1) & 1;
            const short* q = wbase + (kc + 1) * 16384;
            bh[nxt][0] = *(const short8v*)(q);
            bh[nxt][1] = *(const short8v*)(q + 512);
            bl[nxt][0] = *(const short8v*)(q + 1024);
            bl[nxt][1] = *(const short8v*)(q + 1536);
        }
        const bool isT = THERM && (kc < 4);
        short8v ah[4], al[4];
        if (isT) {
            const unsigned int w = (kc == 0) ? tw0 : (kc == 1) ? tw1
                                 : (kc == 2) ? tw2 : tw3;
#pragma unroll
            for (int mi = 0; mi < 4; ++mi) {
                short8v hv;
#pragma unroll
                for (int j = 0; j < 8; ++j)
                    hv[j] = (short)(((w >> (mi * 8 + j)) & 1u) ? 0x3F80 : 0);
                ah[mi] = hv;
            }
        } else {
            const int ki = THERM ? (kc - 4) : kc;
#pragma unroll
            for (int mi = 0; mi < 4; ++mi) {
                ah[mi] = *(const short8v*)(xAh + ((ki * 4 + mi) * 64 + lane) * 8);
                al[mi] = *(const short8v*)(xAl + ((ki * 4 + mi) * 64 + lane) * 8);
            }
        }
#pragma unroll
        for (int mi = 0; mi < 4; ++mi)
#pragma unroll
            for (int nt = 0; nt < 2; ++nt) {
                acc[mi][nt] = mfma_bf16(ah[mi], bh[cur][nt], acc[mi][nt]);
                acc[mi][nt] = mfma_bf16(ah[mi], bl[cur][nt], acc[mi][nt]);
                if (!isT)
                    acc[mi][nt] = mfma_bf16(al[mi], bh[cur][nt], acc[mi][nt]);
            }
    }

    // bias + activation
    float bc0 = bias[wn * 32 + col];
    float bc1 = bias[wn * 32 + 16 + col];
#pragma unroll
    for (int mi = 0; mi < 4; ++mi)
#pragma unroll
        for (int r = 0; r < 4; ++r) {
            float z0 = acc[mi][0][r] + bc0;
            float z1 = acc[mi][1][r] + bc1;
            if (ACT == 0) { z0 = fmaxf(z0, 0.f); z1 = fmaxf(z1, 0.f); }
            else { z0 = (z0 > 0.f) ? z0 : 0.01f * z0; z1 = (z1 > 0.f) ? z1 : 0.01f * z1; }
            acc[mi][0][r] = z0; acc[mi][1][r] = z1;
        }

    __syncthreads();   // all xA reads of this layer done

    if (NORM) {
        float rsum[4][4];
#pragma unroll
        for (int mi = 0; mi < 4; ++mi)
#pragma unroll
            for (int r = 0; r < 4; ++r)
                rsum[mi][r] = quad16_sum(acc[mi][0][r] + acc[mi][1][r]);
        if (col == 0) {
#pragma unroll
            for (int mi = 0; mi < 4; ++mi)
#pragma unroll
                for (int r = 0; r < 4; ++r)
                    ps[wn][mi * 16 + quad * 4 + r] = rsum[mi][r];
        }
        __syncthreads();
        float mu[4][4];
#pragma unroll
        for (int mi = 0; mi < 4; ++mi)
#pragma unroll
            for (int r = 0; r < 4; ++r) {
                int m = mi * 16 + quad * 4 + r;
                float s = 0.f;
#pragma unroll
                for (int w = 0; w < 8; ++w) s += ps[w][m];
                mu[mi][r] = s * (1.f / 256.f);
            }
        __syncthreads();
        float qs[4][4];
#pragma unroll
        for (int mi = 0; mi < 4; ++mi)
#pragma unroll
            for (int r = 0; r < 4; ++r) {
                acc[mi][0][r] -= mu[mi][r];
                acc[mi][1][r] -= mu[mi][r];
                float q = acc[mi][0][r] * acc[mi][0][r]
                        + acc[mi][1][r] * acc[mi][1][r];
                qs[mi][r] = quad16_sum(q);
            }
        if (col == 0) {
#pragma unroll
            for (int mi = 0; mi < 4; ++mi)
#pragma unroll
                for (int r = 0; r < 4; ++r)
                    ps[wn][mi * 16 + quad * 4 + r] = qs[mi][r];
        }
        __syncthreads();
#pragma unroll
        for (int mi = 0; mi < 4; ++mi)
#pragma unroll
            for (int r = 0; r < 4; ++r) {
                int m = mi * 16 + quad * 4 + r;
                float s = 0.f;
#pragma unroll
                for (int w = 0; w < 8; ++w) s += ps[w][m];
                float rsf = 1.0f / sqrtf(s * (1.f / 256.f) + 1e-5f);
                acc[mi][0][r] *= rsf;
                acc[mi][1][r] *= rsf;
            }
    }

    if (SCORE) {
        __syncthreads();
        float sv0 = sW[wn * 32 + col];
        float sv1 = sW[wn * 32 + 16 + col];
        float psu[4][4];
#pragma unroll
        for (int mi = 0; mi < 4; ++mi)
#pragma unroll
            for (int r = 0; r < 4; ++r)
                psu[mi][r] = quad16_sum(acc[mi][0][r] * sv0 + acc[mi][1][r] * sv1);
        if (col == 0) {
#pragma unroll
            for (int mi = 0; mi < 4; ++mi)
#pragma unroll
                for (int r = 0; r < 4; ++r)
                    ps[wn][mi * 16 + quad * 4 + r] = psu[mi][r];
        }
        __syncthreads();
        if (tid < 64) {
            float s = sb[0];
#pragma unroll
            for (int w = 0; w < 8; ++w) s += ps[w][tid];
            scores[R0 + tid] = s;
        }
    } else {
        // writeback to next layer's A-frag layout; wave wn owns k-chunk wn.
#pragma unroll
        for (int mi = 0; mi < 4; ++mi)
#pragma unroll
            for (int nt = 0; nt < 2; ++nt) {
                int nn0 = (nt * 16 + col) & ~1;
                int q2  = nn0 >> 3;
                int j0  = nn0 & 7;
#pragma unroll
                for (int r = 0; r < 4; ++r) {
                    float v  = acc[mi][nt][r];
                    float pv = __shfl_xor(v, 1, 64);
                    int m15 = quad * 4 + r;
                    int rowidx = (wn * 4 + mi) * 64 + q2 * 16 + m15;
                    if ((col & 1) == 0) {
                        unsigned int wd = (unsigned int)bf16_rn(v)
                                        | ((unsigned int)bf16_rn(pv) << 16);
                        ((unsigned int*)xAh)[rowidx * 4 + (j0 >> 1)] = wd;
                    } else {
                        float ls = v  - bf16_val(bf16_rn(v));
                        float lp = pv - bf16_val(bf16_rn(pv));
                        unsigned int wd = (unsigned int)bf16_rn(lp)
                                        | ((unsigned int)bf16_rn(ls) << 16);
                        ((unsigned int*)xAl)[rowidx * 4 + (j0 >> 1)] = wd;
                    }
                }
            }
        __syncthreads();
    }
}

__global__ __launch_bounds__(512, 2) void k_mlp(
    const int* __restrict__ subsets, const short* __restrict__ wprep,
    const short* __restrict__ vertB,
    const float* __restrict__ maskB, const int* __restrict__ eiB,
    const float* __restrict__ cb,  const float* __restrict__ l1b,
    const float* __restrict__ l2ab, const float* __restrict__ l2bb,
    const float* __restrict__ sW,  const float* __restrict__ sb,
    float* __restrict__ scores)
{
    __shared__ __align__(16) char smem[L_TOT];
    short*  xAh = (short*)smem;
    short*  xAl = (short*)(smem + L_XAL);
    short*  fm  = (short*)(smem + L_XAL);          // alias: dead before xAl use
    float (*ps)[64]  = (float(*)[64])(smem + L_PS);
    uint4*  tm       = (uint4*)(smem + L_TM);
    float*  invsz    = (float*)(smem + L_INV);

    const int tid  = threadIdx.x;
    const int lane = tid & 63;
    const int wn   = tid >> 6;
    const int quad = lane >> 4;
    const int col  = lane & 15;
    const int fb   = blockIdx.x;          // 0..511, 64 rows each
    const int b    = fb >> 6;
    const int R0   = fb * 64;

    // ---- phase A1: subset flags -> exact-bf16 A-frags (K=64, k>=48 zero) ----
    {
        int g  = tid;                     // 512 threads = 8 frags x 64 lanes
        int lg = g & 63;
        int t2 = g >> 6;                  // kc*4 + mi
        int kc = t2 >> 2, mi = t2 & 3;
        int m  = mi * 16 + (lg & 15);
        int k0 = kc * 32 + (lg >> 4) * 8;
        const int* srow = subsets + (size_t)(R0 + m) * A_DIM;
        short8v hv;
#pragma unroll
        for (int j = 0; j < 8; ++j) {
            int k = k0 + j;
            hv[j] = (short)((k < A_DIM && srow[k]) ? 0x3F80 : 0);
        }
        *(short8v*)(fm + g * 8) = hv;
    }

    // ---- phase A2: per-row thermometer bitmask (ballot) + 1/subset_size ----
    {
        const float mymask = (lane < A_DIM) ? maskB[b * A_DIM + lane] : 0.f;
        const int   myei   = (lane < A_DIM) ? eiB[b * A_DIM + lane]   : -1;
        unsigned long long* tmw = (unsigned long long*)tm;
#pragma unroll
        for (int i = 0; i < 8; ++i) {
            int r = wn * 8 + i;
            int fl = (lane < A_DIM) ? subsets[(size_t)(R0 + r) * A_DIM + lane] : 0;
            unsigned long long m0 = __ballot(fl != 0 && myei == 0);
            unsigned long long m1 = __ballot(fl != 0 && myei == 1);
            unsigned long long m2 = __ballot(fl != 0 && myei == 2);
            unsigned long long m3 = __ballot(fl != 0 && myei == 3);
            unsigned long long m4 = __ballot(fl != 0 && myei == 4);
            float ssz = wave_sum(fl ? mymask : 0.f) + 1e-4f;
            if (lane == 0) {
                unsigned int c0 = __popcll(m0), c1 = __popcll(m1),
                             c2 = __popcll(m2), c3 = __popcll(m3),
                             c4 = __popcll(m4);
                // thermometer run per element: bits [e*20, e*20+min(c,20))
                unsigned long long r0 = (1ull << (c0 > 20u ? 20u : c0)) - 1ull;
                unsigned long long r1 = (1ull << (c1 > 20u ? 20u : c1)) - 1ull;
                unsigned long long r2 = (1ull << (c2 > 20u ? 20u : c2)) - 1ull;
                unsigned long long r3 = (1ull << (c3 > 20u ? 20u : c3)) - 1ull;
                unsigned long long r4 = (1ull << (c4 > 20u ? 20u : c4)) - 1ull;
                unsigned long long lo = r0 | (r1 << 20) | (r2 << 40) | (r3 << 60);
                unsigned long long hi = (r3 >> 4) | (r4 << 16);
                tmw[r * 2]     = lo;
                tmw[r * 2 + 1] = hi;
                invsz[r]  = 1.0f / ssz;
            }
        }
    }
    __syncthreads();

    // ---- layer 0: sws = flags @ (vert*mask^2), /size, inorm -> combine input
    {
        const short* wbase = vertB + b * 32768 + wn * 2048 + lane * 8;
        float4v acc[4][2];
#pragma unroll
        for (int mi = 0; mi < 4; ++mi)
#pragma unroll
            for (int nt = 0; nt < 2; ++nt) acc[mi][nt] = (float4v){0.f, 0.f, 0.f, 0.f};

        short8v bh[2][2], bl[2][2];
#pragma unroll
        for (int kc = 0; kc < 2; ++kc) {
            const short* q = wbase + kc * 16384;
            bh[kc][0] = *(const short8v*)(q);
            bh[kc][1] = *(const short8v*)(q + 512);
            bl[kc][0] = *(const short8v*)(q + 1024);
            bl[kc][1] = *(const short8v*)(q + 1536);
        }
#pragma unroll
        for (int kc = 0; kc < 2; ++kc) {
#pragma unroll
            for (int mi = 0; mi < 4; ++mi) {
                short8v a = *(const short8v*)(fm + ((kc * 4 + mi) * 64 + lane) * 8);
#pragma unroll
                for (int nt = 0; nt < 2; ++nt) {
                    acc[mi][nt] = mfma_bf16(a, bh[kc][nt], acc[mi][nt]);
                    acc[mi][nt] = mfma_bf16(a, bl[kc][nt], acc[mi][nt]);
                }
            }
        }

        // mean = sws / subset_size
#pragma unroll
        for (int mi = 0; mi < 4; ++mi)
#pragma unroll
            for (int r = 0; r < 4; ++r) {
                float iv = invsz[mi * 16 + quad * 4 + r];
                acc[mi][0][r] *= iv;
                acc[mi][1][r] *= iv;
            }

        __syncthreads();   // fm reads done; xAl region may now be overwritten

        // instance norm over 256 cols
        {
            float rsum[4][4];
#pragma unroll
            for (int mi = 0; mi < 4; ++mi)
#pragma unroll
                for (int r = 0; r < 4; ++r)
                    rsum[mi][r] = quad16_sum(acc[mi][0][r] + acc[mi][1][r]);
            if (col == 0) {
#pragma unroll
                for (int mi = 0; mi < 4; ++mi)
#pragma unroll
                    for (int r = 0; r < 4; ++r)
                        ps[wn][mi * 16 + quad * 4 + r] = rsum[mi][r];
            }
            __syncthreads();
            float mu[4][4];
#pragma unroll
            for (int mi = 0; mi < 4; ++mi)
#pragma unroll
                for (int r = 0; r < 4; ++r) {
                    int m = mi * 16 + quad * 4 + r;
                    float s = 0.f;
#pragma unroll
                    for (int w = 0; w < 8; ++w) s += ps[w][m];
                    mu[mi][r] = s * (1.f / 256.f);
                }
            __syncthreads();
            float qs[4][4];
#pragma unroll
            for (int mi = 0; mi < 4; ++mi)
#pragma unroll
                for (int r = 0; r < 4; ++r) {
                    acc[mi][0][r] -= mu[mi][r];
                    acc[mi][1][r] -= mu[mi][r];
                    float q = acc[mi][0][r] * acc[mi][0][r]
                            + acc[mi][1][r] * acc[mi][1][r];
                    qs[mi][r] = quad16_sum(q);
                }
            if (col == 0) {
#pragma unroll
                for (int mi = 0; mi < 4; ++mi)
#pragma unroll
                    for (int r = 0; r < 4; ++r)
                        ps[wn][mi * 16 + quad * 4 + r] = qs[mi][r];
            }
            __syncthreads();
#pragma unroll
            for (int mi = 0; mi < 4; ++mi)
#pragma unroll
                for (int r = 0; r < 4; ++r) {
                    int m = mi * 16 + quad * 4 + r;
                    float s = 0.f;
#pragma unroll
                    for (int w = 0; w < 8; ++w) s += ps[w][m];
                    float rsf = 1.0f / sqrtf(s * (1.f / 256.f) + 1e-5f);
                    acc[mi][0][r] *= rsf;
                    acc[mi][1][r] *= rsf;
                }
        }

        // writeback: normed cols n -> combine chunks wn (layer 1 reads kc-4)
#pragma unroll
        for (int mi = 0; mi < 4; ++mi)
#pragma unroll
            for (int nt = 0; nt < 2; ++nt) {
                int nn0 = (nt * 16 + col) & ~1;
                int q2  = nn0 >> 3;
                int j0  = nn0 & 7;
#pragma unroll
                for (int r = 0; r < 4; ++r) {
                    float v  = acc[mi][nt][r];
                    float pv = __shfl_xor(v, 1, 64);
                    int m15 = quad * 4 + r;
                    int rowidx = (wn * 4 + mi) * 64 + q2 * 16 + m15;
                    if ((col & 1) == 0) {
                        unsigned int wd = (unsigned int)bf16_rn(v)
                                        | ((unsigned int)bf16_rn(pv) << 16);
                        ((unsigned int*)xAh)[rowidx * 4 + (j0 >> 1)] = wd;
                    } else {
                        float ls = v  - bf16_val(bf16_rn(v));
                        float lp = pv - bf16_val(bf16_rn(pv));
                        unsigned int wd = (unsigned int)bf16_rn(lp)
                                        | ((unsigned int)bf16_rn(ls) << 16);
                        ((unsigned int*)xAl)[rowidx * 4 + (j0 >> 1)] = wd;
                    }
                }
            }
        __syncthreads();
    }

    // ---- layers 1..4 ----
    layer_pass<12, 0, true,  false, true >(xAh, xAl, ps, tm, wprep,
        cb, nullptr, nullptr, nullptr, R0);
    layer_pass< 8, 0, false, false, false>(xAh, xAl, ps, tm, wprep + 12 * 16384,
        l1b, nullptr, nullptr, nullptr, R0);
    layer_pass< 8, 1, false, false, false>(xAh, xAl, ps, tm, wprep + 20 * 16384,
        l2ab, nullptr, nullptr, nullptr, R0);
    layer_pass< 8, 0, true,  true,  false>(xAh, xAl, ps, tm, wprep + 28 * 16384,
        l2bb, sW, sb, scores, R0);
}

// ---------------- softmax / scatter ----------------
__global__ __launch_bounds__(256) void k_softmax(float* __restrict__ probs) {
    const int b   = blockIdx.x;
    const int tid = threadIdx.x;
    __shared__ float redA[4];
    __shared__ float redB[4];
    float* sp = probs + (size_t)b * S_DIM;

    float v[16];
    float mx = -INFINITY;
#pragma unroll
    for (int i = 0; i < 16; ++i) {
        v[i] = sp[tid + i * 256];
        mx = fmaxf(mx, v[i]);
    }
    mx = wave_max(mx);
    if ((tid & 63) == 0) redA[tid >> 6] = mx;
    __syncthreads();
    mx = fmaxf(fmaxf(redA[0], redA[1]), fmaxf(redA[2], redA[3]));

    float sum = 0.f;
#pragma unroll
    for (int i = 0; i < 16; ++i) {
        v[i] = expf(v[i] - mx);
        sum += v[i];
    }
    sum = wave_sum(sum);
    if ((tid & 63) == 0) redB[tid >> 6] = sum;
    __syncthreads();
    float tot = redB[0] + redB[1] + redB[2] + redB[3];
    float inv = 1.0f / tot;
#pragma unroll
    for (int i = 0; i < 16; ++i) sp[tid + i * 256] = v[i] * inv;
}

__global__ __launch_bounds__(256) void k_scatter(
    const int*   __restrict__ mass_idx,
    const float* __restrict__ intensity,
    const float* __restrict__ probs,
    float* __restrict__ spect)
{
    int i  = blockIdx.x * 256 + threadIdx.x;
    int bs = i >> 5;
    int b  = i >> 17;
    float w = intensity[i] * probs[bs];
    unsafeAtomicAdd(spect + ((size_t)b << 16) + mass_idx[i], w);
}

// ---------------- launch ----------------
extern "C" void kernel_launch(void* const* d_in, const int* in_sizes, int n_in,
                              void* d_out, int out_size, void* d_ws, size_t ws_size,
                              hipStream_t stream) {
    const float* vert_feat = (const float*)d_in[0];
    const float* vert_mask = (const float*)d_in[1];
    const float* elem_oh   = (const float*)d_in[2];
    const int*   subsets   = (const int*)d_in[4];
    const int*   mass_idx  = (const int*)d_in[6];
    const float* intensity = (const float*)d_in[7];
    const float* combine_W = (const float*)d_in[8];
    const float* combine_b = (const float*)d_in[9];
    const float* l1_W      = (const float*)d_in[10];
    const float* l1_b      = (const float*)d_in[11];
    const float* l2a_W     = (const float*)d_in[12];
    const float* l2a_b     = (const float*)d_in[13];
    const float* l2b_W     = (const float*)d_in[14];
    const float* l2b_b     = (const float*)d_in[15];
    const float* score_W   = (const float*)d_in[16];
    const float* score_b   = (const float*)d_in[17];

    float* out   = (float*)d_out;
    float* spect = out;                           // B*NBINS
    float* probs = out + (size_t)B_DIM * NBINS;   // B*S (scores -> probs in place)

    short* wprep = (short*)d_ws;                  // 36*16384 shorts
    short* vertB = wprep + 36 * 16384;            // 16*16384 shorts
    float* maskB = (float*)(vertB + 16 * 16384);  // 384 f32
    int*   eiB   = (int*)(maskB + B_DIM * A_DIM); // 384 int

    k_prep<<<2177, 256, 0, stream>>>(combine_W, l1_W, l2a_W, l2b_W,
        vert_feat, vert_mask, elem_oh, wprep, vertB, maskB, eiB,
        (float4*)spect);
    k_mlp<<<512, 512, 0, stream>>>(subsets, wprep, vertB, maskB, eiB,
        combine_b, l1_b, l2a_b, l2b_b, score_W, score_b, probs);
    k_softmax<<<B_DIM, 256, 0, stream>>>(probs);
    k_scatter<<<(B_DIM * S_DIM * P_DIM) / 256, 256, 0, stream>>>(
        mass_idx, intensity, probs, spect);
}

// Round 6
// 245.330 us; speedup vs baseline: 1.1392x; 1.0901x over previous
//
#include <hip/hip_runtime.h>
#include <math.h>

// Problem constants
#define B_DIM 8
#define A_DIM 48
#define GF_DIM 256
#define S_DIM 4096
#define P_DIM 32
#define E_DIM 5
#define OHN 100
#define NBINS 65536

typedef __attribute__((ext_vector_type(8))) short short8v;
typedef __attribute__((ext_vector_type(4))) float float4v;

// ---------------- helpers ----------------
__device__ __forceinline__ float wave_sum(float v) {
#pragma unroll
    for (int o = 32; o; o >>= 1) v += __shfl_xor(v, o, 64);
    return v;
}
__device__ __forceinline__ float wave_max(float v) {
#pragma unroll
    for (int o = 32; o; o >>= 1) v = fmaxf(v, __shfl_xor(v, o, 64));
    return v;
}
__device__ __forceinline__ float quad16_sum(float v) {
    v += __shfl_xor(v, 1, 64); v += __shfl_xor(v, 2, 64);
    v += __shfl_xor(v, 4, 64); v += __shfl_xor(v, 8, 64);
    return v;
}
__device__ __forceinline__ unsigned short bf16_rn(float x) {
    unsigned int u = __float_as_uint(x);
    return (unsigned short)((u + 0x7FFFu + ((u >> 16) & 1u)) >> 16);
}
__device__ __forceinline__ float bf16_val(unsigned short h) {
    return __uint_as_float(((unsigned int)h) << 16);
}
__device__ __forceinline__ float4v mfma_bf16(short8v a, short8v b, float4v c) {
    return __builtin_amdgcn_mfma_f32_16x16x32_bf16(a, b, c, 0, 0, 0);
}

// ---------------- prep: W hi/lo streams + vert*mask^2 + mask/ei + zero spect -
__global__ __launch_bounds__(256) void k_prep(
    const float* __restrict__ cW, const float* __restrict__ l1W,
    const float* __restrict__ l2aW, const float* __restrict__ l2bW,
    const float* __restrict__ vert_feat, const float* __restrict__ vert_mask,
    const float* __restrict__ elem_oh,
    short* __restrict__ wp, short* __restrict__ wv,
    float* __restrict__ maskB, int* __restrict__ eiB,
    float4* __restrict__ spect4)
{
    const int blk = blockIdx.x;
    const int tid = threadIdx.x;
    if (blk < 1152) {
        int e = blk * 256 + tid;              // < 36*8192
        int c = e >> 13;
        int i = e & 8191;
        int j    = i & 7;
        int lane = (i >> 3) & 63;
        int nt   = (i >> 9) & 1;
        int wn   = i >> 10;
        int krel = (lane >> 4) * 8 + j;
        int n    = wn * 32 + nt * 16 + (lane & 15);
        float val = 0.f;
        if (c < 12) {
            int kp = c * 32 + krel;
            if (kp < 100)       val = cW[kp * 256 + n];
            else if (kp >= 128) val = cW[(kp - 28) * 256 + n];
        } else {
            int L  = (c - 12) >> 3;
            int kc = (c - 12) & 7;
            const float* W = (L == 0) ? l1W : (L == 1) ? l2aW : l2bW;
            val = W[(kc * 32 + krel) * 256 + n];
        }
        unsigned short h = bf16_rn(val);
        float lo = val - bf16_val(h);
        int base = c * 16384 + (i & 511);
        wp[base + (wn * 4 + nt) * 512]     = (short)h;
        wp[base + (wn * 4 + 2 + nt) * 512] = (short)bf16_rn(lo);
    } else if (blk < 1664) {
        int vb = blk - 1152;
        int vc = vb >> 5;                     // 0..15
        int i  = (vb & 31) * 256 + tid;       // 0..8191
        int b  = vc >> 1, v = vc & 1;
        int j    = i & 7;
        int lane = (i >> 3) & 63;
        int nt   = (i >> 9) & 1;
        int wn   = i >> 10;
        int k = v * 32 + (lane >> 4) * 8 + j;
        int n = wn * 32 + nt * 16 + (lane & 15);
        float val = 0.f;
        if (k < A_DIM) {
            float mk = vert_mask[b * A_DIM + k];
            val = vert_feat[((size_t)(b * A_DIM + k)) * GF_DIM + n] * mk * mk;
        }
        unsigned short h = bf16_rn(val);
        float lo = val - bf16_val(h);
        int base = vc * 16384 + (i & 511);
        wv[base + (wn * 4 + nt) * 512]     = (short)h;
        wv[base + (wn * 4 + 2 + nt) * 512] = (short)bf16_rn(lo);
    } else if (blk == 1664) {
        // grid-stride: 384 entries with 256 threads
        for (int t = tid; t < B_DIM * A_DIM; t += 256) {
            maskB[t] = vert_mask[t];
            int ei = 0;
#pragma unroll
            for (int e = 0; e < E_DIM; ++e)
                if (elem_oh[t * E_DIM + e] > 0.5f) ei = e;
            eiB[t] = ei;
        }
    } else {
        // zero spect: 512 blocks x 256 thr x float4 = 524288 f32
        int z = (blk - 1665) * 256 + tid;
        spect4[z] = make_float4(0.f, 0.f, 0.f, 0.f);
    }
}

// ---------------- MLP kernel ------------------------------------------------
// BEST-KNOWN CONFIG (R1, k_mlp 110.68us): M=32/block, 1024 blocks, 512 thr,
// launch_bounds(512,4), ring-3 W prefetch, 3-pass norm, THERM regen.
// R2-R5 post-mortems: reg-squeeze+fused-norm (spill, 141us), A ping-pong
// (132us), M=64 @(512,4) (spill, 136us), M=64 @(512,2) (125us, occupancy
// halved) — all regressed. This structure is the measured local optimum.
// LDS layout (34432 B):
//   xAh  [0,     16384)  8 chunks (inter-layer hi)
//   xAl  [16384, 32768)  8 chunks (lo); fm (4096 B) aliased at xAl base
//   ps   [32768, 33792)  1024
//   tm   [33792, 34304)  32 rows x 16 B thermometer bitmask
//   invsz[34304, 34432)  128
#define L_XAL 16384
#define L_PS  32768
#define L_TM  33792
#define L_INV 34304
#define L_TOT 34432

// One GEMM layer, barrier-free K loop; W slice in regs (depth-2 prefetch).
// THERM: kc 0..3 A-frags regenerated from thermometer bitmask (exact bf16,
// hi-only, 2 mfma); kc 4..11 read xAh/xAl chunk kc-4 (3 mfma).
template <int NKC, int ACT, bool NORM, bool SCORE, bool THERM>
__device__ __forceinline__ void layer_pass(
    short* xAh, short* xAl, float (*ps)[32], const uint4* __restrict__ tm,
    const short* __restrict__ wstream, const float* __restrict__ bias,
    const float* __restrict__ sW, const float* __restrict__ sb,
    float* __restrict__ scores, int R0)
{
    const int tid  = threadIdx.x;
    const int lane = tid & 63;
    const int wn   = tid >> 6;
    const int quad = lane >> 4;
    const int col  = lane & 15;
    const short* wbase = wstream + wn * 2048 + lane * 8;

    // packed thermometer bits: tw01 = {kc0: mi0 byte | mi1 byte<<8,
    //                                  kc1: <<16|<<24}, tw23 likewise.
    unsigned int tw01 = 0, tw23 = 0;
    if (THERM) {
        const int sh = quad * 8;
        uint4 t0 = tm[col];        // row m = col      (mi=0)
        uint4 t1 = tm[16 + col];   // row m = 16+col   (mi=1)
        tw01 = ((t0.x >> sh) & 0xFFu)        | (((t1.x >> sh) & 0xFFu) << 8)
             | (((t0.y >> sh) & 0xFFu) << 16) | (((t1.y >> sh) & 0xFFu) << 24);
        tw23 = ((t0.z >> sh) & 0xFFu)        | (((t1.z >> sh) & 0xFFu) << 8)
             | (((t0.w >> sh) & 0xFFu) << 16) | (((t1.w >> sh) & 0xFFu) << 24);
    }

    float4v acc[2][2];
#pragma unroll
    for (int mi = 0; mi < 2; ++mi)
#pragma unroll
        for (int nt = 0; nt < 2; ++nt) acc[mi][nt] = (float4v){0.f, 0.f, 0.f, 0.f};

    short8v bh[3][2], bl[3][2];
#pragma unroll
    for (int p = 0; p < 2; ++p) {
        if (p < NKC) {
            const short* q = wbase + p * 16384;
            bh[p][0] = *(const short8v*)(q);
            bh[p][1] = *(const short8v*)(q + 512);
            bl[p][0] = *(const short8v*)(q + 1024);
            bl[p][1] = *(const short8v*)(q + 1536);
        }
    }

#pragma unroll
    for (int kc = 0; kc < NKC; ++kc) {
        const int cur = kc % 3;
        if (kc + 2 < NKC) {
            const int nxt = (kc + 2) % 3;
            const short* q = wbase + (kc + 2) * 16384;
            bh[nxt][0] = *(const short8v*)(q);
            bh[nxt][1] = *(const short8v*)(q + 512);
            bl[nxt][0] = *(const short8v*)(q + 1024);
            bl[nxt][1] = *(const short8v*)(q + 1536);
        }
        const bool isT = THERM && (kc < 4);
        short8v ah[2], al[2];
        if (isT) {
            const unsigned int w = (kc < 2) ? tw01 : tw23;
#pragma unroll
            for (int mi = 0; mi < 2; ++mi) {
                const int bb = (kc & 1) * 16 + mi * 8;
                short8v hv;
#pragma unroll
                for (int j = 0; j < 8; ++j)
                    hv[j] = (short)(((w >> (bb + j)) & 1u) ? 0x3F80 : 0);
                ah[mi] = hv;
            }
        } else {
            const int ki = THERM ? (kc - 4) : kc;
#pragma unroll
            for (int mi = 0; mi < 2; ++mi) {
                ah[mi] = *(const short8v*)(xAh + ((ki * 2 + mi) * 64 + lane) * 8);
                al[mi] = *(const short8v*)(xAl + ((ki * 2 + mi) * 64 + lane) * 8);
            }
        }
#pragma unroll
        for (int mi = 0; mi < 2; ++mi)
#pragma unroll
            for (int nt = 0; nt < 2; ++nt) {
                acc[mi][nt] = mfma_bf16(ah[mi], bh[cur][nt], acc[mi][nt]);
                acc[mi][nt] = mfma_bf16(ah[mi], bl[cur][nt], acc[mi][nt]);
                if (!isT)
                    acc[mi][nt] = mfma_bf16(al[mi], bh[cur][nt], acc[mi][nt]);
            }
    }

    // bias + activation
    float bc0 = bias[wn * 32 + col];
    float bc1 = bias[wn * 32 + 16 + col];
#pragma unroll
    for (int mi = 0; mi < 2; ++mi)
#pragma unroll
        for (int r = 0; r < 4; ++r) {
            float z0 = acc[mi][0][r] + bc0;
            float z1 = acc[mi][1][r] + bc1;
            if (ACT == 0) { z0 = fmaxf(z0, 0.f); z1 = fmaxf(z1, 0.f); }
            else { z0 = (z0 > 0.f) ? z0 : 0.01f * z0; z1 = (z1 > 0.f) ? z1 : 0.01f * z1; }
            acc[mi][0][r] = z0; acc[mi][1][r] = z1;
        }

    __syncthreads();   // all xA reads of this layer done

    if (NORM) {
        float rsum[2][4];
#pragma unroll
        for (int mi = 0; mi < 2; ++mi)
#pragma unroll
            for (int r = 0; r < 4; ++r)
                rsum[mi][r] = quad16_sum(acc[mi][0][r] + acc[mi][1][r]);
        if (col == 0) {
#pragma unroll
            for (int mi = 0; mi < 2; ++mi)
#pragma unroll
                for (int r = 0; r < 4; ++r)
                    ps[wn][mi * 16 + quad * 4 + r] = rsum[mi][r];
        }
        __syncthreads();
        float mu[2][4];
#pragma unroll
        for (int mi = 0; mi < 2; ++mi)
#pragma unroll
            for (int r = 0; r < 4; ++r) {
                int m = mi * 16 + quad * 4 + r;
                float s = 0.f;
#pragma unroll
                for (int w = 0; w < 8; ++w) s += ps[w][m];
                mu[mi][r] = s * (1.f / 256.f);
            }
        __syncthreads();
        float qs[2][4];
#pragma unroll
        for (int mi = 0; mi < 2; ++mi)
#pragma unroll
            for (int r = 0; r < 4; ++r) {
                acc[mi][0][r] -= mu[mi][r];
                acc[mi][1][r] -= mu[mi][r];
                float q = acc[mi][0][r] * acc[mi][0][r]
                        + acc[mi][1][r] * acc[mi][1][r];
                qs[mi][r] = quad16_sum(q);
            }
        if (col == 0) {
#pragma unroll
            for (int mi = 0; mi < 2; ++mi)
#pragma unroll
                for (int r = 0; r < 4; ++r)
                    ps[wn][mi * 16 + quad * 4 + r] = qs[mi][r];
        }
        __syncthreads();
#pragma unroll
        for (int mi = 0; mi < 2; ++mi)
#pragma unroll
            for (int r = 0; r < 4; ++r) {
                int m = mi * 16 + quad * 4 + r;
                float s = 0.f;
#pragma unroll
                for (int w = 0; w < 8; ++w) s += ps[w][m];
                float rsf = 1.0f / sqrtf(s * (1.f / 256.f) + 1e-5f);
                acc[mi][0][r] *= rsf;
                acc[mi][1][r] *= rsf;
            }
    }

    if (SCORE) {
        __syncthreads();
        float sv0 = sW[wn * 32 + col];
        float sv1 = sW[wn * 32 + 16 + col];
        float psu[2][4];
#pragma unroll
        for (int mi = 0; mi < 2; ++mi)
#pragma unroll
            for (int r = 0; r < 4; ++r)
                psu[mi][r] = quad16_sum(acc[mi][0][r] * sv0 + acc[mi][1][r] * sv1);
        if (col == 0) {
#pragma unroll
            for (int mi = 0; mi < 2; ++mi)
#pragma unroll
                for (int r = 0; r < 4; ++r)
                    ps[wn][mi * 16 + quad * 4 + r] = psu[mi][r];
        }
        __syncthreads();
        if (tid < 32) {
            float s = sb[0];
#pragma unroll
            for (int w = 0; w < 8; ++w) s += ps[w][tid];
            scores[R0 + tid] = s;
        }
    } else {
        // writeback to next layer's A-frag layout; wave wn owns k-chunk wn.
#pragma unroll
        for (int mi = 0; mi < 2; ++mi)
#pragma unroll
            for (int nt = 0; nt < 2; ++nt) {
                int nn0 = (nt * 16 + col) & ~1;
                int q2  = nn0 >> 3;
                int j0  = nn0 & 7;
#pragma unroll
                for (int r = 0; r < 4; ++r) {
                    float v  = acc[mi][nt][r];
                    float pv = __shfl_xor(v, 1, 64);
                    int m15 = quad * 4 + r;
                    int rowidx = (wn * 2 + mi) * 64 + q2 * 16 + m15;
                    if ((col & 1) == 0) {
                        unsigned int wd = (unsigned int)bf16_rn(v)
                                        | ((unsigned int)bf16_rn(pv) << 16);
                        ((unsigned int*)xAh)[rowidx * 4 + (j0 >> 1)] = wd;
                    } else {
                        float ls = v  - bf16_val(bf16_rn(v));
                        float lp = pv - bf16_val(bf16_rn(pv));
                        unsigned int wd = (unsigned int)bf16_rn(lp)
                                        | ((unsigned int)bf16_rn(ls) << 16);
                        ((unsigned int*)xAl)[rowidx * 4 + (j0 >> 1)] = wd;
                    }
                }
            }
        __syncthreads();
    }
}

__global__ __launch_bounds__(512, 4) void k_mlp(
    const int* __restrict__ subsets, const short* __restrict__ wprep,
    const short* __restrict__ vertB,
    const float* __restrict__ maskB, const int* __restrict__ eiB,
    const float* __restrict__ cb,  const float* __restrict__ l1b,
    const float* __restrict__ l2ab, const float* __restrict__ l2bb,
    const float* __restrict__ sW,  const float* __restrict__ sb,
    float* __restrict__ scores)
{
    __shared__ __align__(16) char smem[L_TOT];
    short*  xAh = (short*)smem;
    short*  xAl = (short*)(smem + L_XAL);
    short*  fm  = (short*)(smem + L_XAL);          // alias: dead before xAl use
    float (*ps)[32]  = (float(*)[32])(smem + L_PS);
    uint4*  tm       = (uint4*)(smem + L_TM);
    float*  invsz    = (float*)(smem + L_INV);

    const int tid  = threadIdx.x;
    const int lane = tid & 63;
    const int wn   = tid >> 6;
    const int quad = lane >> 4;
    const int col  = lane & 15;
    const int fb   = blockIdx.x;          // 0..1023, 32 rows each
    const int b    = fb >> 7;
    const int R0   = fb * 32;

    // ---- phase A1: subset flags -> exact-bf16 A-frags (K=64, k>=48 zero) ----
    if (tid < 256) {
        int g  = tid;
        int lg = g & 63;
        int t2 = g >> 6;                  // kc*2 + mi
        int kc = t2 >> 1, mi = t2 & 1;
        int m  = mi * 16 + (lg & 15);
        int k0 = kc * 32 + (lg >> 4) * 8;
        const int* srow = subsets + (size_t)(R0 + m) * A_DIM;
        short8v hv;
#pragma unroll
        for (int j = 0; j < 8; ++j) {
            int k = k0 + j;
            hv[j] = (short)((k < A_DIM && srow[k]) ? 0x3F80 : 0);
        }
        *(short8v*)(fm + g * 8) = hv;
    }

    // ---- phase A2: per-row thermometer bitmask (ballot) + 1/subset_size ----
    {
        const float mymask = (lane < A_DIM) ? maskB[b * A_DIM + lane] : 0.f;
        const int   myei   = (lane < A_DIM) ? eiB[b * A_DIM + lane]   : -1;
        unsigned long long* tmw = (unsigned long long*)tm;
#pragma unroll
        for (int i = 0; i < 4; ++i) {
            int r = wn * 4 + i;
            int fl = (lane < A_DIM) ? subsets[(size_t)(R0 + r) * A_DIM + lane] : 0;
            unsigned long long m0 = __ballot(fl != 0 && myei == 0);
            unsigned long long m1 = __ballot(fl != 0 && myei == 1);
            unsigned long long m2 = __ballot(fl != 0 && myei == 2);
            unsigned long long m3 = __ballot(fl != 0 && myei == 3);
            unsigned long long m4 = __ballot(fl != 0 && myei == 4);
            float ssz = wave_sum(fl ? mymask : 0.f) + 1e-4f;
            if (lane == 0) {
                unsigned int c0 = __popcll(m0), c1 = __popcll(m1),
                             c2 = __popcll(m2), c3 = __popcll(m3),
                             c4 = __popcll(m4);
                // thermometer run per element: bits [e*20, e*20+min(c,20))
                unsigned long long r0 = (1ull << (c0 > 20u ? 20u : c0)) - 1ull;
                unsigned long long r1 = (1ull << (c1 > 20u ? 20u : c1)) - 1ull;
                unsigned long long r2 = (1ull << (c2 > 20u ? 20u : c2)) - 1ull;
                unsigned long long r3 = (1ull << (c3 > 20u ? 20u : c3)) - 1ull;
                unsigned long long r4 = (1ull << (c4 > 20u ? 20u : c4)) - 1ull;
                unsigned long long lo = r0 | (r1 << 20) | (r2 << 40) | (r3 << 60);
                unsigned long long hi = (r3 >> 4) | (r4 << 16);
                tmw[r * 2]     = lo;
                tmw[r * 2 + 1] = hi;
                invsz[r]  = 1.0f / ssz;
            }
        }
    }
    __syncthreads();

    // ---- layer 0: sws = flags @ (vert*mask^2), /size, inorm -> combine input
    {
        const short* wbase = vertB + b * 32768 + wn * 2048 + lane * 8;
        float4v acc[2][2];
#pragma unroll
        for (int mi = 0; mi < 2; ++mi)
#pragma unroll
            for (int nt = 0; nt < 2; ++nt) acc[mi][nt] = (float4v){0.f, 0.f, 0.f, 0.f};

        short8v bh[2][2], bl[2][2];
#pragma unroll
        for (int kc = 0; kc < 2; ++kc) {
            const short* q = wbase + kc * 16384;
            bh[kc][0] = *(const short8v*)(q);
            bh[kc][1] = *(const short8v*)(q + 512);
            bl[kc][0] = *(const short8v*)(q + 1024);
            bl[kc][1] = *(const short8v*)(q + 1536);
        }
#pragma unroll
        for (int kc = 0; kc < 2; ++kc) {
            short8v a0 = *(const short8v*)(fm + ((kc * 2 + 0) * 64 + lane) * 8);
            short8v a1 = *(const short8v*)(fm + ((kc * 2 + 1) * 64 + lane) * 8);
#pragma unroll
            for (int nt = 0; nt < 2; ++nt) {
                acc[0][nt] = mfma_bf16(a0, bh[kc][nt], acc[0][nt]);
                acc[0][nt] = mfma_bf16(a0, bl[kc][nt], acc[0][nt]);
                acc[1][nt] = mfma_bf16(a1, bh[kc][nt], acc[1][nt]);
                acc[1][nt] = mfma_bf16(a1, bl[kc][nt], acc[1][nt]);
            }
        }

        // mean = sws / subset_size
#pragma unroll
        for (int mi = 0; mi < 2; ++mi)
#pragma unroll
            for (int r = 0; r < 4; ++r) {
                float iv = invsz[mi * 16 + quad * 4 + r];
                acc[mi][0][r] *= iv;
                acc[mi][1][r] *= iv;
            }

        __syncthreads();   // fm reads done; xAl region may now be overwritten

        // instance norm over 256 cols
        {
            float rsum[2][4];
#pragma unroll
            for (int mi = 0; mi < 2; ++mi)
#pragma unroll
                for (int r = 0; r < 4; ++r)
                    rsum[mi][r] = quad16_sum(acc[mi][0][r] + acc[mi][1][r]);
            if (col == 0) {
#pragma unroll
                for (int mi = 0; mi < 2; ++mi)
#pragma unroll
                    for (int r = 0; r < 4; ++r)
                        ps[wn][mi * 16 + quad * 4 + r] = rsum[mi][r];
            }
            __syncthreads();
            float mu[2][4];
#pragma unroll
            for (int mi = 0; mi < 2; ++mi)
#pragma unroll
                for (int r = 0; r < 4; ++r) {
                    int m = mi * 16 + quad * 4 + r;
                    float s = 0.f;
#pragma unroll
                    for (int w = 0; w < 8; ++w) s += ps[w][m];
                    mu[mi][r] = s * (1.f / 256.f);
                }
            __syncthreads();
            float qs[2][4];
#pragma unroll
            for (int mi = 0; mi < 2; ++mi)
#pragma unroll
                for (int r = 0; r < 4; ++r) {
                    acc[mi][0][r] -= mu[mi][r];
                    acc[mi][1][r] -= mu[mi][r];
                    float q = acc[mi][0][r] * acc[mi][0][r]
                            + acc[mi][1][r] * acc[mi][1][r];
                    qs[mi][r] = quad16_sum(q);
                }
            if (col == 0) {
#pragma unroll
                for (int mi = 0; mi < 2; ++mi)
#pragma unroll
                    for (int r = 0; r < 4; ++r)
                        ps[wn][mi * 16 + quad * 4 + r] = qs[mi][r];
            }
            __syncthreads();
#pragma unroll
            for (int mi = 0; mi < 2; ++mi)
#pragma unroll
                for (int r = 0; r < 4; ++r) {
                    int m = mi * 16 + quad * 4 + r;
                    float s = 0.f;
#pragma unroll
                    for (int w = 0; w < 8; ++w) s += ps[w][m];
                    float rsf = 1.0f / sqrtf(s * (1.f / 256.f) + 1e-5f);
                    acc[mi][0][r] *= rsf;
                    acc[mi][1][r] *= rsf;
                }
        }

        // writeback: normed cols n -> combine chunks wn (layer 1 reads kc-4)
#pragma unroll
        for (int mi = 0; mi < 2; ++mi)
#pragma unroll
            for (int nt = 0; nt < 2; ++nt) {
                int nn0 = (nt * 16 + col) & ~1;
                int q2  = nn0 >> 3;
                int j0  = nn0 & 7;
#pragma unroll
                for (int r = 0; r < 4; ++r) {
                    float v  = acc[mi][nt][r];
                    float pv = __shfl_xor(v, 1, 64);
                    int m15 = quad * 4 + r;
                    int rowidx = (wn * 2 + mi) * 64 + q2 * 16 + m15;
                    if ((col & 1) == 0) {
                        unsigned int wd = (unsigned int)bf16_rn(v)
                                        | ((unsigned int)bf16_rn(pv) << 16);
                        ((unsigned int*)xAh)[rowidx * 4 + (j0 >> 1)] = wd;
                    } else {
                        float ls = v  - bf16_val(bf16_rn(v));
                        float lp = pv - bf16_val(bf16_rn(pv));
                        unsigned int wd = (unsigned int)bf16_rn(lp)
                                        | ((unsigned int)bf16_rn(ls) << 16);
                        ((unsigned int*)xAl)[rowidx * 4 + (j0 >> 1)] = wd;
                    }
                }
            }
        __syncthreads();
    }

    // ---- layers 1..4 ----
    layer_pass<12, 0, true,  false, true >(xAh, xAl, ps, tm, wprep,
        cb, nullptr, nullptr, nullptr, R0);
    layer_pass< 8, 0, false, false, false>(xAh, xAl, ps, tm, wprep + 12 * 16384,
        l1b, nullptr, nullptr, nullptr, R0);
    layer_pass< 8, 1, false, false, false>(xAh, xAl, ps, tm, wprep + 20 * 16384,
        l2ab, nullptr, nullptr, nullptr, R0);
    layer_pass< 8, 0, true,  true,  false>(xAh, xAl, ps, tm, wprep + 28 * 16384,
        l2bb, sW, sb, scores, R0);
}

// ---------------- softmax / scatter ----------------
__global__ __launch_bounds__(256) void k_softmax(float* __restrict__ probs) {
    const int b   = blockIdx.x;
    const int tid = threadIdx.x;
    __shared__ float redA[4];
    __shared__ float redB[4];
    float* sp = probs + (size_t)b * S_DIM;

    float v[16];
    float mx = -INFINITY;
#pragma unroll
    for (int i = 0; i < 16; ++i) {
        v[i] = sp[tid + i * 256];
        mx = fmaxf(mx, v[i]);
    }
    mx = wave_max(mx);
    if ((tid & 63) == 0) redA[tid >> 6] = mx;
    __syncthreads();
    mx = fmaxf(fmaxf(redA[0], redA[1]), fmaxf(redA[2], redA[3]));

    float sum = 0.f;
#pragma unroll
    for (int i = 0; i < 16; ++i) {
        v[i] = expf(v[i] - mx);
        sum += v[i];
    }
    sum = wave_sum(sum);
    if ((tid & 63) == 0) redB[tid >> 6] = sum;
    __syncthreads();
    float tot = redB[0] + redB[1] + redB[2] + redB[3];
    float inv = 1.0f / tot;
#pragma unroll
    for (int i = 0; i < 16; ++i) sp[tid + i * 256] = v[i] * inv;
}

// 4 peaks/thread (all share the same bs since i % 4 == 0 within a 32-group):
// one probs broadcast per 4 atomics, int4/float4 coalesced loads.
__global__ __launch_bounds__(256) void k_scatter(
    const int*   __restrict__ mass_idx,
    const float* __restrict__ intensity,
    const float* __restrict__ probs,
    float* __restrict__ spect)
{
    int g  = blockIdx.x * 256 + threadIdx.x;   // 0..262143
    int i  = g << 2;
    int bs = i >> 5;
    int b  = i >> 17;
    float p = probs[bs];
    int4   m4 = *(const int4*)(mass_idx + i);
    float4 w4 = *(const float4*)(intensity + i);
    float* sb = spect + ((size_t)b << 16);
    unsafeAtomicAdd(sb + m4.x, w4.x * p);
    unsafeAtomicAdd(sb + m4.y, w4.y * p);
    unsafeAtomicAdd(sb + m4.z, w4.z * p);
    unsafeAtomicAdd(sb + m4.w, w4.w * p);
}

// ---------------- launch ----------------
extern "C" void kernel_launch(void* const* d_in, const int* in_sizes, int n_in,
                              void* d_out, int out_size, void* d_ws, size_t ws_size,
                              hipStream_t stream) {
    const float* vert_feat = (const float*)d_in[0];
    const float* vert_mask = (const float*)d_in[1];
    const float* elem_oh   = (const float*)d_in[2];
    const int*   subsets   = (const int*)d_in[4];
    const int*   mass_idx  = (const int*)d_in[6];
    const float* intensity = (const float*)d_in[7];
    const float* combine_W = (const float*)d_in[8];
    const float* combine_b = (const float*)d_in[9];
    const float* l1_W      = (const float*)d_in[10];
    const float* l1_b      = (const float*)d_in[11];
    const float* l2a_W     = (const float*)d_in[12];
    const float* l2a_b     = (const float*)d_in[13];
    const float* l2b_W     = (const float*)d_in[14];
    const float* l2b_b     = (const float*)d_in[15];
    const float* score_W   = (const float*)d_in[16];
    const float* score_b   = (const float*)d_in[17];

    float* out   = (float*)d_out;
    float* spect = out;                           // B*NBINS
    float* probs = out + (size_t)B_DIM * NBINS;   // B*S (scores -> probs in place)

    short* wprep = (short*)d_ws;                  // 36*16384 shorts
    short* vertB = wprep + 36 * 16384;            // 16*16384 shorts
    float* maskB = (float*)(vertB + 16 * 16384);  // 384 f32
    int*   eiB   = (int*)(maskB + B_DIM * A_DIM); // 384 int

    k_prep<<<2177, 256, 0, stream>>>(combine_W, l1_W, l2a_W, l2b_W,
        vert_feat, vert_mask, elem_oh, wprep, vertB, maskB, eiB,
        (float4*)spect);
    k_mlp<<<1024, 512, 0, stream>>>(subsets, wprep, vertB, maskB, eiB,
        combine_b, l1_b, l2a_b, l2b_b, score_W, score_b, probs);
    k_softmax<<<B_DIM, 256, 0, stream>>>(probs);
    k_scatter<<<(B_DIM * S_DIM * P_DIM) / (256 * 4), 256, 0, stream>>>(
        mass_idx, intensity, probs, spect);
}